// Round 9
// baseline (280.118 us; speedup 1.0000x reference)
//
#include <hip/hip_runtime.h>
#include <stdint.h>
#include <stddef.h>

#define DIM 1024
#define EPS 1e-8f

typedef int   v8i    __attribute__((ext_vector_type(8)));
typedef int   i32x4  __attribute__((ext_vector_type(4)));
typedef float f32x16 __attribute__((ext_vector_type(16)));

// async global->LDS, 16B per lane, wave-uniform LDS base + lane*16
__device__ __forceinline__ void async_copy16(const void* g, void* l) {
    __builtin_amdgcn_global_load_lds(
        (__attribute__((address_space(1))) void*)const_cast<void*>(g),
        (__attribute__((address_space(3))) void*)(l), 16, 0, 0);
}

// drain all but newest N vmem ops, then barrier (R6-verified discipline)
#define PIPE_SYNC(N) asm volatile("s_waitcnt vmcnt(" #N ")\n\ts_barrier" ::: "memory")

// ---------------------------------------------------------------------------
// Prep: wave-per-row. Unit-normalize, scale by 16 (undone in epilogue), cast
// to OCP fp8 e4m3. PLAIN k-order rows (32x32x64 MX fragments read 32
// consecutive k-bytes per lane — no permutation needed). Lane L owns
// elements [16L,16L+16): 4 contiguous float4 loads, one coalesced uint4
// store. x-rows also emit exact fp32 positive sim + zero rowsum.
// ---------------------------------------------------------------------------
__global__ __launch_bounds__(256)
void prep_all(const float* __restrict__ x, const float* __restrict__ pos,
              const float* __restrict__ neg,
              unsigned char* __restrict__ Xn, unsigned char* __restrict__ Nn,
              float* __restrict__ simOut, float* __restrict__ rowsum, int bn) {
    const int lane = threadIdx.x & 63;
    const int wave = threadIdx.x >> 6;
    const int grow = blockIdx.x * 4 + wave;
    const bool isX = grow < bn;
    const int row  = isX ? grow : grow - bn;
    const float* src = isX ? x : neg;
    unsigned char* dst = isX ? Xn : Nn;

    const float4* s = (const float4*)(src + (size_t)row * DIM);
    float4 xv[4], pv[4];
    float sxx = 0.f, spp = 0.f, sxp = 0.f;
#pragma unroll
    for (int i = 0; i < 4; i++) {
        xv[i] = s[lane * 4 + i];
        sxx += xv[i].x * xv[i].x + xv[i].y * xv[i].y + xv[i].z * xv[i].z + xv[i].w * xv[i].w;
    }
    if (isX) {
        const float4* p = (const float4*)(pos + (size_t)row * DIM);
#pragma unroll
        for (int i = 0; i < 4; i++) {
            pv[i] = p[lane * 4 + i];
            spp += pv[i].x * pv[i].x + pv[i].y * pv[i].y + pv[i].z * pv[i].z + pv[i].w * pv[i].w;
            sxp += xv[i].x * pv[i].x + xv[i].y * pv[i].y + xv[i].z * pv[i].z + xv[i].w * pv[i].w;
        }
#pragma unroll
        for (int off = 1; off < 64; off <<= 1) {
            sxx += __shfl_xor(sxx, off);
            spp += __shfl_xor(spp, off);
            sxp += __shfl_xor(sxp, off);
        }
    } else {
#pragma unroll
        for (int off = 1; off < 64; off <<= 1) sxx += __shfl_xor(sxx, off);
    }
    const float nx  = sqrtf(sxx);
    const float inv = (nx > 0.f) ? (16.f / nx) : 0.f;   // x16 -> e4m3 sweet spot
    if (isX && lane == 0) {
        const float np = sqrtf(spp);
        simOut[row] = sxp / fmaxf(nx * np, EPS);
        rowsum[row] = 0.f;
    }
    uint4 w;
    unsigned int t;
    t   = __builtin_amdgcn_cvt_pk_fp8_f32(xv[0].x * inv, xv[0].y * inv, 0, false);
    w.x = __builtin_amdgcn_cvt_pk_fp8_f32(xv[0].z * inv, xv[0].w * inv, t, true);
    t   = __builtin_amdgcn_cvt_pk_fp8_f32(xv[1].x * inv, xv[1].y * inv, 0, false);
    w.y = __builtin_amdgcn_cvt_pk_fp8_f32(xv[1].z * inv, xv[1].w * inv, t, true);
    t   = __builtin_amdgcn_cvt_pk_fp8_f32(xv[2].x * inv, xv[2].y * inv, 0, false);
    w.z = __builtin_amdgcn_cvt_pk_fp8_f32(xv[2].z * inv, xv[2].w * inv, t, true);
    t   = __builtin_amdgcn_cvt_pk_fp8_f32(xv[3].x * inv, xv[3].y * inv, 0, false);
    w.w = __builtin_amdgcn_cvt_pk_fp8_f32(xv[3].z * inv, xv[3].w * inv, t, true);
    ((uint4*)(dst + (size_t)row * DIM))[lane] = w;
}

// ---------------------------------------------------------------------------
// Fused MX-fp8 GEMM: rowsum[i] += sum_j exp( (Xn8[i]/16 . Nn8[j]/16) )
// R6 skeleton verbatim: 128x128 tile, 4 waves, BK=64-B windows, THREE-stage
// LDS (48 KB), distance-2 prefetch via s_waitcnt vmcnt(4)+s_barrier.
// Inner compute: mfma_scale_f32_32x32x64_f8f6f4 (K=64 = one window, scales
// =1.0 via E8M0 0x7F) — 4 MX MFMAs/phase @2x fp8 rate replace 32 fp8 MFMAs.
// Per wave 64x64 out = 2x2 of 32x32 tiles (acc 2x2 f32x16 = 64 VGPR).
// A-frag: lane L holds A[m=L&31][k=(L>>5)*32 + 0..31] -> 2 ds_read_b128 at
// chunks c,c^1 (c=2*(L>>5)), phys = c ^ ((row>>1)&3). Per 16-lane group:
// 16 distinct rows x 1 chunk x XOR-key spread = R1/R6-verified conflict-free.
// ---------------------------------------------------------------------------
__global__ __launch_bounds__(256)
void gemm_exp_rowsum(const unsigned char* __restrict__ Xn,
                     const unsigned char* __restrict__ Nn,
                     float* __restrict__ rowsum) {
    constexpr int KB   = DIM;        // 1024 bytes per fp8 row
    constexpr int BK   = 64;         // bytes per stage-row (one K=64 window)
    constexpr int BUFB = 128 * BK;   // 8 KB per buffer
    __shared__ __align__(16) unsigned char Ash[3][BUFB];
    __shared__ __align__(16) unsigned char Bsh[3][BUFB];

    const int tid  = threadIdx.x;
    const int lane = tid & 63;
    const int wave = tid >> 6;
    const int rowBase = blockIdx.y * 128;
    const int colBase = blockIdx.x * 128;

    // staging: one glds = 1 KB = 16 rows x 64 B; lane -> (row, chunk)
    const int srow   = lane >> 2;                       // 0..15
    const int schunk = (lane & 3) ^ ((srow >> 1) & 3);  // global-side swizzle
    const unsigned char* gA = Xn + (size_t)(rowBase + wave * 16 + srow) * KB + schunk * 16;
    const unsigned char* gB = Nn + (size_t)(colBase + wave * 16 + srow) * KB + schunk * 16;
    const int lgrp0 = (wave * 16) * BK;
    const int lgrp1 = (wave * 16 + 64) * BK;

    f32x16 acc[2][2];
#pragma unroll
    for (int mi = 0; mi < 2; mi++)
#pragma unroll
        for (int ni = 0; ni < 2; ni++)
#pragma unroll
            for (int r = 0; r < 16; r++) acc[mi][ni][r] = 0.f;

    const int m0   = (wave >> 1) * 64;
    const int n0   = (wave & 1) * 64;
    const int mrow = lane & 31;               // fragment row/col (32x32)
    const int half = lane >> 5;               // k-half: k = half*32 + 0..31
    const int key  = (mrow >> 1) & 3;         // read-side swizzle key
    const int cphy = ((half << 1) ^ key) << 4; // first-b128 byte offset in row

    int aoff[2], boff[2];
#pragma unroll
    for (int i = 0; i < 2; i++) {
        aoff[i] = (m0 + i * 32 + mrow) * BK + cphy;
        boff[i] = (n0 + i * 32 + mrow) * BK + cphy;
    }

#define STAGE(buf, stg)                                                  \
    do {                                                                 \
        const int kq = (stg) * BK;                                       \
        async_copy16(gA + kq,            &Ash[buf][lgrp0]);              \
        async_copy16(gA + 64 * KB + kq,  &Ash[buf][lgrp1]);              \
        async_copy16(gB + kq,            &Bsh[buf][lgrp0]);              \
        async_copy16(gB + 64 * KB + kq,  &Bsh[buf][lgrp1]);              \
    } while (0)

#define COMPUTE(buf)                                                     \
    do {                                                                 \
        v8i a2[2], b2[2];                                                \
        _Pragma("unroll")                                                \
        for (int i = 0; i < 2; i++) {                                    \
            *(i32x4*)&a2[i]       = *(const i32x4*)&Ash[buf][aoff[i]];   \
            *((i32x4*)&a2[i] + 1) = *(const i32x4*)&Ash[buf][aoff[i] ^ 16]; \
            *(i32x4*)&b2[i]       = *(const i32x4*)&Bsh[buf][boff[i]];   \
            *((i32x4*)&b2[i] + 1) = *(const i32x4*)&Bsh[buf][boff[i] ^ 16]; \
        }                                                                \
        _Pragma("unroll")                                                \
        for (int mi = 0; mi < 2; mi++)                                   \
            _Pragma("unroll")                                            \
            for (int ni = 0; ni < 2; ni++)                               \
                acc[mi][ni] = __builtin_amdgcn_mfma_scale_f32_32x32x64_f8f6f4( \
                    a2[mi], b2[ni], acc[mi][ni], 0, 0,                   \
                    0, 0x7F7F7F7F, 0, 0x7F7F7F7F);                       \
    } while (0)

    STAGE(0, 0);
    STAGE(1, 1);
    // 16 stages; stage s computed at phase s in buffer s%3, staged 2 ahead
    for (int it = 0; it < 4; it++) {
        const int s = 3 * it + 2;
        PIPE_SYNC(4); STAGE(2, s);     COMPUTE(0);
        PIPE_SYNC(4); STAGE(0, s + 1); COMPUTE(1);
        PIPE_SYNC(4); STAGE(1, s + 2); COMPUTE(2);
    }
    PIPE_SYNC(4); STAGE(2, 14); COMPUTE(0);   // stage 12
    PIPE_SYNC(4); STAGE(0, 15); COMPUTE(1);   // stage 13
    PIPE_SYNC(4);               COMPUTE(2);   // stage 14
    PIPE_SYNC(0);               COMPUTE(0);   // stage 15
#undef STAGE
#undef COMPUTE

    // epilogue: undo x16*x16 scaling (1/256), exp, reduce over 32 cols.
    // 32x32 C/D layout: col=lane&31, row=(reg&3)+8*(reg>>2)+4*(lane>>5).
#pragma unroll
    for (int mi = 0; mi < 2; mi++)
#pragma unroll
        for (int r = 0; r < 16; r++) {
            float v = __expf(acc[mi][0][r] * 0.00390625f)
                    + __expf(acc[mi][1][r] * 0.00390625f);
#pragma unroll
            for (int off = 1; off < 32; off <<= 1) v += __shfl_xor(v, off);
            if (mrow == 0) {
                const int rloc = (r & 3) + 8 * (r >> 2) + 4 * half;
                atomicAdd(&rowsum[rowBase + m0 + mi * 32 + rloc], v);
            }
        }
}

__global__ __launch_bounds__(1024)
void loss_kernel(const float* __restrict__ rowsum, const float* __restrict__ sim,
                 float* __restrict__ out, int bn) {
    const int tid  = threadIdx.x;
    const int lane = tid & 63;
    const int wave = tid >> 6;
    float acc = 0.f;
    for (int i = tid; i < bn; i += 1024) acc += logf(rowsum[i]) - sim[i];
#pragma unroll
    for (int off = 1; off < 64; off <<= 1) acc += __shfl_xor(acc, off);
    __shared__ float red[16];
    if (lane == 0) red[wave] = acc;
    __syncthreads();
    if (tid == 0) {
        float t = 0.f;
#pragma unroll
        for (int i = 0; i < 16; i++) t += red[i];
        out[0] = t / (float)bn;
    }
}

extern "C" void kernel_launch(void* const* d_in, const int* in_sizes, int n_in,
                              void* d_out, int out_size, void* d_ws, size_t ws_size,
                              hipStream_t stream) {
    const float* x   = (const float*)d_in[0];
    const float* pos = (const float*)d_in[1];
    const float* neg = (const float*)d_in[2];
    const int bn = in_sizes[0] / DIM;  // 4096
    const int cn = in_sizes[2] / DIM;  // 8192

    // ws layout: Xn fp8 [bn*DIM] | Nn fp8 [cn*DIM] | sim f32 [bn] | rowsum f32 [bn]
    unsigned char* Xn = (unsigned char*)d_ws;
    unsigned char* Nn = Xn + (size_t)bn * DIM;
    float* sim    = (float*)(Nn + (size_t)cn * DIM);
    float* rowsum = sim + bn;

    prep_all<<<dim3((bn + cn) / 4), dim3(256), 0, stream>>>(
        x, pos, neg, Xn, Nn, sim, rowsum, bn);
    gemm_exp_rowsum<<<dim3(cn / 128, bn / 128), dim3(256), 0, stream>>>(Xn, Nn, rowsum);
    loss_kernel<<<dim3(1), dim3(1024), 0, stream>>>(rowsum, sim, (float*)d_out, bn);
}

// Round 10
// 167.646 us; speedup vs baseline: 1.6709x; 1.6709x over previous
//
#include <hip/hip_runtime.h>
#include <stdint.h>
#include <stddef.h>

#define DIM 1024
#define EPS 1e-8f

typedef __attribute__((ext_vector_type(4))) float f32x4;
typedef __attribute__((ext_vector_type(2))) long longx2;   // 16 B = 2 fp8 k-halves

// async global->LDS, 16B per lane, wave-uniform LDS base + lane*16
__device__ __forceinline__ void async_copy16(const void* g, void* l) {
    __builtin_amdgcn_global_load_lds(
        (__attribute__((address_space(1))) void*)const_cast<void*>(g),
        (__attribute__((address_space(3))) void*)(l), 16, 0, 0);
}

// drain all but newest N vmem ops, then barrier (R6-verified discipline)
#define PIPE_SYNC(N) asm volatile("s_waitcnt vmcnt(" #N ")\n\ts_barrier" ::: "memory")

// ---------------------------------------------------------------------------
// Prep: wave-per-row. Unit-normalize, scale by 16 (undone in epilogue), cast
// to OCP fp8 e4m3. Rows stored PERMUTED per 64-B k-window: 16-B chunk q
// holds bytes [q*8,+8) and [32+q*8,+8) of the window so the GEMM fetches
// both k-steps of a quad-fragment with ONE ds_read_b128 (R6-verified zero
// bank conflicts). x-rows also emit exact fp32 positive sim + zero rowsum.
// ---------------------------------------------------------------------------
__global__ __launch_bounds__(256)
void prep_all(const float* __restrict__ x, const float* __restrict__ pos,
              const float* __restrict__ neg,
              unsigned char* __restrict__ Xn, unsigned char* __restrict__ Nn,
              float* __restrict__ simOut, float* __restrict__ rowsum, int bn) {
    const int lane = threadIdx.x & 63;
    const int wave = threadIdx.x >> 6;
    const int grow = blockIdx.x * 4 + wave;
    const bool isX = grow < bn;
    const int row  = isX ? grow : grow - bn;
    const float* src = isX ? x : neg;
    unsigned char* dst = isX ? Xn : Nn;

    const float4* s = (const float4*)(src + (size_t)row * DIM);
    float4 xv[4], pv[4];
    float sxx = 0.f, spp = 0.f, sxp = 0.f;
#pragma unroll
    for (int i = 0; i < 4; i++) {
        xv[i] = s[lane + 64 * i];
        sxx += xv[i].x * xv[i].x + xv[i].y * xv[i].y + xv[i].z * xv[i].z + xv[i].w * xv[i].w;
    }
    if (isX) {
        const float4* p = (const float4*)(pos + (size_t)row * DIM);
#pragma unroll
        for (int i = 0; i < 4; i++) {
            pv[i] = p[lane + 64 * i];
            spp += pv[i].x * pv[i].x + pv[i].y * pv[i].y + pv[i].z * pv[i].z + pv[i].w * pv[i].w;
            sxp += xv[i].x * pv[i].x + xv[i].y * pv[i].y + xv[i].z * pv[i].z + xv[i].w * pv[i].w;
        }
#pragma unroll
        for (int off = 1; off < 64; off <<= 1) {
            sxx += __shfl_xor(sxx, off);
            spp += __shfl_xor(spp, off);
            sxp += __shfl_xor(sxp, off);
        }
    } else {
#pragma unroll
        for (int off = 1; off < 64; off <<= 1) sxx += __shfl_xor(sxx, off);
    }
    const float nx  = sqrtf(sxx);
    const float inv = (nx > 0.f) ? (16.f / nx) : 0.f;   // x16 -> e4m3 sweet spot
    if (isX && lane == 0) {
        const float np = sqrtf(spp);
        simOut[row] = sxp / fmaxf(nx * np, EPS);
        rowsum[row] = 0.f;
    }
    unsigned int t;
    t = __builtin_amdgcn_cvt_pk_fp8_f32(xv[0].x * inv, xv[0].y * inv, 0, false);
    unsigned int q0 = __builtin_amdgcn_cvt_pk_fp8_f32(xv[0].z * inv, xv[0].w * inv, t, true);
    t = __builtin_amdgcn_cvt_pk_fp8_f32(xv[1].x * inv, xv[1].y * inv, 0, false);
    unsigned int q1 = __builtin_amdgcn_cvt_pk_fp8_f32(xv[1].z * inv, xv[1].w * inv, t, true);
    t = __builtin_amdgcn_cvt_pk_fp8_f32(xv[2].x * inv, xv[2].y * inv, 0, false);
    unsigned int q2 = __builtin_amdgcn_cvt_pk_fp8_f32(xv[2].z * inv, xv[2].w * inv, t, true);
    t = __builtin_amdgcn_cvt_pk_fp8_f32(xv[3].x * inv, xv[3].y * inv, 0, false);
    unsigned int q3 = __builtin_amdgcn_cvt_pk_fp8_f32(xv[3].z * inv, xv[3].w * inv, t, true);

    const int m  = lane & 3;
    const int d0 = (m & 1) * 32 + (m >> 1) * 8;          // 0,32,8,40
    unsigned char* wbase = dst + (size_t)row * DIM + (lane >> 2) * 64;
    *(unsigned long long*)(wbase + d0)      = ((unsigned long long)q1 << 32) | q0;
    *(unsigned long long*)(wbase + d0 + 16) = ((unsigned long long)q3 << 32) | q2;
}

// ---------------------------------------------------------------------------
// Fused fp8 GEMM: rowsum[i] += sum_j exp( (Xn8[i]/16 . Nn8[j]/16) )
// 128x128 tile, BK=64 B (permuted windows), 3-stage LDS (48 KB), prefetch
// distance 2 via s_waitcnt vmcnt(4)+s_barrier. Per phase: 8 ds_read_b128
// (each feeds TWO mfma_f32_16x16x32_fp8_fp8 k-steps) + 32 MFMA.
// Chunk swizzle: physical chunk = logical ^ ((row>>1)&3) — with b128 reads
// this tiles all 32 banks per 16-lane group (R6-measured zero conflicts).
// This exact configuration measured 77 µs / MfmaUtil 36 / 0 conflicts (R6);
// variants tried and rejected: distance-1 2-stage (R1/R8), lgkm-gated
// 2-stage (R7), 256x128 tile (R8), MX 32x32x64 (R9) — all >= 86 µs.
// ---------------------------------------------------------------------------
__global__ __launch_bounds__(256)
void gemm_exp_rowsum(const unsigned char* __restrict__ Xn,
                     const unsigned char* __restrict__ Nn,
                     float* __restrict__ rowsum) {
    constexpr int KB   = DIM;        // 1024 bytes per fp8 row
    constexpr int BK   = 64;         // bytes per stage-row (one permuted window)
    constexpr int BUFB = 128 * BK;   // 8 KB per buffer
    __shared__ __align__(16) unsigned char Ash[3][BUFB];
    __shared__ __align__(16) unsigned char Bsh[3][BUFB];

    const int tid  = threadIdx.x;
    const int lane = tid & 63;
    const int wave = tid >> 6;
    const int rowBase = blockIdx.y * 128;
    const int colBase = blockIdx.x * 128;

    // staging: one glds = 1 KB = 16 rows x 64 B; lane -> (row, chunk)
    const int srow   = lane >> 2;                       // 0..15
    const int schunk = (lane & 3) ^ ((srow >> 1) & 3);  // global-side swizzle
    const unsigned char* gA = Xn + (size_t)(rowBase + wave * 16 + srow) * KB + schunk * 16;
    const unsigned char* gB = Nn + (size_t)(colBase + wave * 16 + srow) * KB + schunk * 16;
    const int lgrp0 = (wave * 16) * BK;
    const int lgrp1 = (wave * 16 + 64) * BK;

    const f32x4 fz = {0.f, 0.f, 0.f, 0.f};
    f32x4 acc[4][4];
#pragma unroll
    for (int mi = 0; mi < 4; mi++)
#pragma unroll
        for (int ni = 0; ni < 4; ni++) acc[mi][ni] = fz;

    const int m0   = (wave >> 1) * 64;
    const int n0   = (wave & 1) * 64;
    const int quad = lane >> 4;
    const int mrow = lane & 15;
    const int kx   = (mrow >> 1) & 3;    // read-side swizzle key

    int aoff[4], boff[4];
#pragma unroll
    for (int i = 0; i < 4; i++) {
        aoff[i] = (m0 + i * 16 + mrow) * BK + ((quad ^ kx) << 4);
        boff[i] = (n0 + i * 16 + mrow) * BK + ((quad ^ kx) << 4);
    }

#define STAGE(buf, stg)                                                  \
    do {                                                                 \
        const int kq = (stg) * BK;                                       \
        async_copy16(gA + kq,            &Ash[buf][lgrp0]);              \
        async_copy16(gA + 64 * KB + kq,  &Ash[buf][lgrp1]);              \
        async_copy16(gB + kq,            &Bsh[buf][lgrp0]);              \
        async_copy16(gB + 64 * KB + kq,  &Bsh[buf][lgrp1]);              \
    } while (0)

#define COMPUTE(buf)                                                     \
    do {                                                                 \
        longx2 a2[4], b2[4];                                             \
        _Pragma("unroll")                                                \
        for (int i = 0; i < 4; i++) {                                    \
            a2[i] = *(const longx2*)&Ash[buf][aoff[i]];                  \
            b2[i] = *(const longx2*)&Bsh[buf][boff[i]];                  \
        }                                                                \
        _Pragma("unroll")                                                \
        for (int mi = 0; mi < 4; mi++)                                   \
            _Pragma("unroll")                                            \
            for (int ni = 0; ni < 4; ni++) {                             \
                acc[mi][ni] = __builtin_amdgcn_mfma_f32_16x16x32_fp8_fp8( \
                    a2[mi].x, b2[ni].x, acc[mi][ni], 0, 0, 0);           \
                acc[mi][ni] = __builtin_amdgcn_mfma_f32_16x16x32_fp8_fp8( \
                    a2[mi].y, b2[ni].y, acc[mi][ni], 0, 0, 0);           \
            }                                                            \
    } while (0)

    STAGE(0, 0);
    STAGE(1, 1);
    // 16 stages; stage s computed at phase s in buffer s%3, staged 2 ahead
    for (int it = 0; it < 4; it++) {
        const int s = 3 * it + 2;
        PIPE_SYNC(4); STAGE(2, s);     COMPUTE(0);
        PIPE_SYNC(4); STAGE(0, s + 1); COMPUTE(1);
        PIPE_SYNC(4); STAGE(1, s + 2); COMPUTE(2);
    }
    PIPE_SYNC(4); STAGE(2, 14); COMPUTE(0);   // stage 12
    PIPE_SYNC(4); STAGE(0, 15); COMPUTE(1);   // stage 13
    PIPE_SYNC(4);               COMPUTE(2);   // stage 14
    PIPE_SYNC(0);               COMPUTE(0);   // stage 15
#undef STAGE
#undef COMPUTE

    // epilogue: undo x16*x16 scaling (1/256), exp, 16-col reduce, atomics.
    // C/D layout: col=lane&15, row=quad*4+reg.
#pragma unroll
    for (int mi = 0; mi < 4; mi++) {
        float rs0 = 0.f, rs1 = 0.f, rs2 = 0.f, rs3 = 0.f;
#pragma unroll
        for (int ni = 0; ni < 4; ni++) {
            rs0 += __expf(acc[mi][ni].x * 0.00390625f);
            rs1 += __expf(acc[mi][ni].y * 0.00390625f);
            rs2 += __expf(acc[mi][ni].z * 0.00390625f);
            rs3 += __expf(acc[mi][ni].w * 0.00390625f);
        }
#pragma unroll
        for (int off = 1; off < 16; off <<= 1) {
            rs0 += __shfl_xor(rs0, off);
            rs1 += __shfl_xor(rs1, off);
            rs2 += __shfl_xor(rs2, off);
            rs3 += __shfl_xor(rs3, off);
        }
        if ((lane & 15) == 0) {
            const int r = rowBase + m0 + mi * 16 + quad * 4;
            atomicAdd(&rowsum[r + 0], rs0);
            atomicAdd(&rowsum[r + 1], rs1);
            atomicAdd(&rowsum[r + 2], rs2);
            atomicAdd(&rowsum[r + 3], rs3);
        }
    }
}

__global__ __launch_bounds__(1024)
void loss_kernel(const float* __restrict__ rowsum, const float* __restrict__ sim,
                 float* __restrict__ out, int bn) {
    const int tid  = threadIdx.x;
    const int lane = tid & 63;
    const int wave = tid >> 6;
    float acc = 0.f;
    for (int i = tid; i < bn; i += 1024) acc += logf(rowsum[i]) - sim[i];
#pragma unroll
    for (int off = 1; off < 64; off <<= 1) acc += __shfl_xor(acc, off);
    __shared__ float red[16];
    if (lane == 0) red[wave] = acc;
    __syncthreads();
    if (tid == 0) {
        float t = 0.f;
#pragma unroll
        for (int i = 0; i < 16; i++) t += red[i];
        out[0] = t / (float)bn;
    }
}

extern "C" void kernel_launch(void* const* d_in, const int* in_sizes, int n_in,
                              void* d_out, int out_size, void* d_ws, size_t ws_size,
                              hipStream_t stream) {
    const float* x   = (const float*)d_in[0];
    const float* pos = (const float*)d_in[1];
    const float* neg = (const float*)d_in[2];
    const int bn = in_sizes[0] / DIM;  // 4096
    const int cn = in_sizes[2] / DIM;  // 8192

    // ws layout: Xn fp8 [bn*DIM] | Nn fp8 [cn*DIM] | sim f32 [bn] | rowsum f32 [bn]
    unsigned char* Xn = (unsigned char*)d_ws;
    unsigned char* Nn = Xn + (size_t)bn * DIM;
    float* sim    = (float*)(Nn + (size_t)cn * DIM);
    float* rowsum = sim + bn;

    prep_all<<<dim3((bn + cn) / 4), dim3(256), 0, stream>>>(
        x, pos, neg, Xn, Nn, sim, rowsum, bn);
    gemm_exp_rowsum<<<dim3(cn / 128, bn / 128), dim3(256), 0, stream>>>(Xn, Nn, rowsum);
    loss_kernel<<<dim3(1), dim3(1024), 0, stream>>>(rowsum, sim, (float*)d_out, bn);
}